// Round 1
// baseline (781.369 us; speedup 1.0000x reference)
//
#include <hip/hip_runtime.h>

// Problem geometry (fixed by the reference)
#define SPATIAL 32768            // D*H*W = 32*32*32
#define NB 4                     // batch
#define CDIM 128                 // channels / embedding dim
#define KCODES 1024              // number of codes
#define NROWS (NB * SPATIAL)     // 131072 rows
#define CHUNK 64                 // codes staged in LDS per iteration
#define NCHUNK (KCODES / CHUNK)

// Output layout in d_out (all float32, concatenated in return order)
#define Q_SIZE (NB * CDIM * SPATIAL)     // 16777216  quantized_st [B,C,D,H,W]
#define LOSS_OFF Q_SIZE                  // 1 scalar
#define IDX_OFF (Q_SIZE + 1)             // 131072 indices (as float)
#define ESUM_OFF (IDX_OFF + NROWS)       // 256 zeros
#define EMB_OFF (ESUM_OFF + 256)         // 131072 emb passthrough

#define MAIN_BLOCKS (NROWS / 256)        // 512

__global__ __launch_bounds__(256) void esq_kernel(const float* __restrict__ emb,
                                                  float* __restrict__ esq) {
    int k = blockIdx.x * 256 + threadIdx.x;
    if (k >= KCODES) return;
    const float4* e = reinterpret_cast<const float4*>(emb + (size_t)k * CDIM);
    float s = 0.f;
#pragma unroll
    for (int i = 0; i < CDIM / 4; i++) {
        float4 v = e[i];
        s = fmaf(v.x, v.x, s);
        s = fmaf(v.y, v.y, s);
        s = fmaf(v.z, v.z, s);
        s = fmaf(v.w, v.w, s);
    }
    esq[k] = s;
}

__global__ __launch_bounds__(256, 2) void vq_main(const float* __restrict__ in,
                                                  const float* __restrict__ emb,
                                                  const float* __restrict__ esq,
                                                  float* __restrict__ out,
                                                  float* __restrict__ partial) {
    __shared__ float4 eL[CHUNK * CDIM / 4];   // 32 KB: chunk of codebook
    __shared__ float esqL[CHUNK];
    __shared__ float red[256];

    const int tid = threadIdx.x;
    const int r = blockIdx.x * 256 + tid;     // row id
    const int b = r >> 15;                    // batch
    const int s = r & (SPATIAL - 1);          // spatial index

    // Load this row's x: inputs[b][c][s], stride SPATIAL over c.
    // Coalesced across lanes (consecutive s).
    const float* xin = in + (size_t)b * CDIM * SPATIAL + s;
    float4 xv[CDIM / 4];
#pragma unroll
    for (int i = 0; i < CDIM / 4; i++) {
        xv[i].x = xin[(size_t)(4 * i + 0) * SPATIAL];
        xv[i].y = xin[(size_t)(4 * i + 1) * SPATIAL];
        xv[i].z = xin[(size_t)(4 * i + 2) * SPATIAL];
        xv[i].w = xin[(size_t)(4 * i + 3) * SPATIAL];
    }

    float best = 3.4e38f;
    int bk = 0;

    for (int ch = 0; ch < NCHUNK; ch++) {
        // Stage 64 codes (32 KB) cooperatively, coalesced float4 loads.
        const float4* src = reinterpret_cast<const float4*>(emb + (size_t)ch * CHUNK * CDIM);
#pragma unroll
        for (int i = 0; i < (CHUNK * CDIM / 4) / 256; i++)
            eL[tid + 256 * i] = src[tid + 256 * i];
        if (tid < CHUNK) esqL[tid] = esq[ch * CHUNK + tid];
        __syncthreads();

        for (int kk = 0; kk < CHUNK; kk++) {
            const float4* ev = &eL[kk * (CDIM / 4)];   // uniform address -> LDS broadcast
            float4 a0 = {0.f, 0.f, 0.f, 0.f}, a1 = {0.f, 0.f, 0.f, 0.f};
            float4 a2 = {0.f, 0.f, 0.f, 0.f}, a3 = {0.f, 0.f, 0.f, 0.f};
#pragma unroll
            for (int i = 0; i < CDIM / 16; i++) {
                float4 e0 = ev[4 * i + 0], e1 = ev[4 * i + 1];
                float4 e2 = ev[4 * i + 2], e3 = ev[4 * i + 3];
                float4 x0 = xv[4 * i + 0], x1 = xv[4 * i + 1];
                float4 x2 = xv[4 * i + 2], x3 = xv[4 * i + 3];
                a0.x = fmaf(x0.x, e0.x, a0.x); a0.y = fmaf(x0.y, e0.y, a0.y);
                a0.z = fmaf(x0.z, e0.z, a0.z); a0.w = fmaf(x0.w, e0.w, a0.w);
                a1.x = fmaf(x1.x, e1.x, a1.x); a1.y = fmaf(x1.y, e1.y, a1.y);
                a1.z = fmaf(x1.z, e1.z, a1.z); a1.w = fmaf(x1.w, e1.w, a1.w);
                a2.x = fmaf(x2.x, e2.x, a2.x); a2.y = fmaf(x2.y, e2.y, a2.y);
                a2.z = fmaf(x2.z, e2.z, a2.z); a2.w = fmaf(x2.w, e2.w, a2.w);
                a3.x = fmaf(x3.x, e3.x, a3.x); a3.y = fmaf(x3.y, e3.y, a3.y);
                a3.z = fmaf(x3.z, e3.z, a3.z); a3.w = fmaf(x3.w, e3.w, a3.w);
            }
            float dot = ((a0.x + a0.y) + (a0.z + a0.w)) + ((a1.x + a1.y) + (a1.z + a1.w)) +
                        ((a2.x + a2.y) + (a2.z + a2.w)) + ((a3.x + a3.y) + (a3.z + a3.w));
            // d' = ||e||^2 - 2 x.e  (== distance - ||x||^2; same argmin)
            float d = fmaf(-2.f, dot, esqL[kk]);
            int kg = ch * CHUNK + kk;
            if (d < best) { best = d; bk = kg; }   // strict '<' => first-occurrence tie-break
        }
        __syncthreads();
    }

    // index output (float representation)
    out[IDX_OFF + r] = (float)bk;

    // Fused epilogue: gather code row, write quantized (channel-first), accumulate loss.
    const float* eb = emb + (size_t)bk * CDIM;
    float* qout = out + (size_t)b * CDIM * SPATIAL + s;
    float lsum = 0.f;
#pragma unroll
    for (int i = 0; i < CDIM / 4; i++) {
        float q0 = eb[4 * i + 0], q1 = eb[4 * i + 1];
        float q2 = eb[4 * i + 2], q3 = eb[4 * i + 3];
        float4 x = xv[i];
        float d0 = q0 - x.x, d1 = q1 - x.y, d2 = q2 - x.z, d3 = q3 - x.w;
        lsum = fmaf(d0, d0, lsum);
        lsum = fmaf(d1, d1, lsum);
        lsum = fmaf(d2, d2, lsum);
        lsum = fmaf(d3, d3, lsum);
        qout[(size_t)(4 * i + 0) * SPATIAL] = q0;
        qout[(size_t)(4 * i + 1) * SPATIAL] = q1;
        qout[(size_t)(4 * i + 2) * SPATIAL] = q2;
        qout[(size_t)(4 * i + 3) * SPATIAL] = q3;
    }

    // deterministic block reduction of loss partial
    red[tid] = lsum;
    __syncthreads();
#pragma unroll
    for (int off = 128; off > 0; off >>= 1) {
        if (tid < off) red[tid] += red[tid + off];
        __syncthreads();
    }
    if (tid == 0) partial[blockIdx.x] = red[0];
}

__global__ __launch_bounds__(512) void finalize_kernel(const float* __restrict__ partial,
                                                       float* __restrict__ out) {
    __shared__ float red[512];
    int t = threadIdx.x;
    red[t] = partial[t];   // MAIN_BLOCKS == 512
    __syncthreads();
#pragma unroll
    for (int off = 256; off > 0; off >>= 1) {
        if (t < off) red[t] += red[t + off];
        __syncthreads();
    }
    if (t == 0) out[LOSS_OFF] = 0.25f * red[0] / (float)Q_SIZE;
}

extern "C" void kernel_launch(void* const* d_in, const int* in_sizes, int n_in,
                              void* d_out, int out_size, void* d_ws, size_t ws_size,
                              hipStream_t stream) {
    const float* in = (const float*)d_in[0];    // [4,128,32,32,32] fp32
    const float* emb = (const float*)d_in[1];   // [1024,128] fp32
    float* out = (float*)d_out;

    float* esq = (float*)d_ws;                  // 1024 floats
    float* partial = esq + KCODES;              // 512 floats

    // encodings_sum: 256 zeros
    hipMemsetAsync(out + ESUM_OFF, 0, 256 * sizeof(float), stream);
    // emb_weight passthrough
    hipMemcpyAsync(out + EMB_OFF, emb, (size_t)KCODES * CDIM * sizeof(float),
                   hipMemcpyDeviceToDevice, stream);

    esq_kernel<<<KCODES / 256, 256, 0, stream>>>(emb, esq);
    vq_main<<<MAIN_BLOCKS, 256, 0, stream>>>(in, emb, esq, out, partial);
    finalize_kernel<<<1, 512, 0, stream>>>(partial, out);
}

// Round 2
// 401.449 us; speedup vs baseline: 1.9464x; 1.9464x over previous
//
#include <hip/hip_runtime.h>

// Problem geometry (fixed by the reference)
#define SPATIAL 32768            // D*H*W
#define NB 4
#define CDIM 128
#define KCODES 1024
#define NROWS (NB * SPATIAL)     // 131072

// Output layout in d_out (all float32, concatenated in return order)
#define Q_SIZE (NB * CDIM * SPATIAL)     // 16777216
#define LOSS_OFF Q_SIZE
#define IDX_OFF (Q_SIZE + 1)
#define ESUM_OFF (IDX_OFF + NROWS)
#define EMB_OFF (ESUM_OFF + 256)

#define SBM 128                  // scoring rows per block
#define SCORE_BLOCKS (NROWS / SBM)   // 1024
#define MARGIN 0.05f
#define CAP 4096
#define FINF 3.4e38f

typedef short short8 __attribute__((ext_vector_type(8)));
typedef float f32x4 __attribute__((ext_vector_type(4)));

static __device__ __forceinline__ unsigned short f2bf(float x) {
    unsigned u = __float_as_uint(x);
    unsigned r = (u + 0x7fffu + ((u >> 16) & 1u)) >> 16;   // RN-even
    return (unsigned short)r;
}
static __device__ __forceinline__ float bf2f(unsigned short h) {
    return __uint_as_float(((unsigned)h) << 16);
}

// ---- prep: emb -> bf16 hi/lo splits + exact ||e||^2 -------------------------
__global__ __launch_bounds__(256) void prep_kernel(const float* __restrict__ emb,
                                                   unsigned short* __restrict__ Ehi,
                                                   unsigned short* __restrict__ Elo,
                                                   float* __restrict__ esq) {
    int k = blockIdx.x * 256 + threadIdx.x;
    if (k >= KCODES) return;
    const float* e = emb + (size_t)k * CDIM;
    unsigned short* hp = Ehi + (size_t)k * CDIM;
    unsigned short* lp = Elo + (size_t)k * CDIM;
    float s = 0.f;
#pragma unroll 8
    for (int c = 0; c < CDIM; c++) {
        float v = e[c];
        unsigned short hb = f2bf(v);
        float hf = bf2f(hb);
        unsigned short lb = f2bf(v - hf);
        hp[c] = hb; lp[c] = lb;
        s = fmaf(v, v, s);
    }
    esq[k] = s;
}

// ---- scoring: MFMA bf16x3, top-1 idx + top-2 value, flag ambiguous ----------
__global__ __launch_bounds__(256) void score_kernel(const float* __restrict__ in,
                                                    const unsigned short* __restrict__ Ehi,
                                                    const unsigned short* __restrict__ Elo,
                                                    const float* __restrict__ esq,
                                                    int* __restrict__ idx_ws,
                                                    int* __restrict__ flag_list,
                                                    int* __restrict__ flag_cnt) {
    __shared__ int4 Ah4[SBM * 16];      // 32 KB each: [row][16 granules of 8 bf16]
    __shared__ int4 Al4[SBM * 16];
    __shared__ int4 Bh4[128 * 16];
    __shared__ int4 Bl4[128 * 16];
    __shared__ float mb1[2][SBM], mb2[2][SBM];
    __shared__ int   mi1[2][SBM];

    const int tid = threadIdx.x;
    const int lane = tid & 63;
    const int w = tid >> 6;                   // wave 0..3
    const int row0 = blockIdx.x * SBM;
    const int b = row0 >> 15;
    const int s0 = row0 & (SPATIAL - 1);

    const int cl = tid & 127;                 // local row / code
    const int h = tid >> 7;                   // granule half

    // ---- prefetch B(ct=0) into regs
    int4 pbh[8], pbl[8];
    {
        const int4* sh = reinterpret_cast<const int4*>(Ehi + (size_t)cl * CDIM);
        const int4* sl = reinterpret_cast<const int4*>(Elo + (size_t)cl * CDIM);
#pragma unroll
        for (int gi = 0; gi < 8; gi++) { pbh[gi] = sh[h * 8 + gi]; pbl[gi] = sl[h * 8 + gi]; }
    }

    // ---- stage A (x rows): load strided fp32, split to bf16 hi/lo, swizzled LDS write
    {
        const float* xb = in + (size_t)b * CDIM * SPATIAL + s0 + cl;
#pragma unroll
        for (int gi = 0; gi < 8; gi++) {
            int g = h * 8 + gi;
            unsigned hp[4], lp[4];
#pragma unroll
            for (int p = 0; p < 4; p++) {
                float v0 = xb[(size_t)(g * 8 + 2 * p + 0) * SPATIAL];
                float v1 = xb[(size_t)(g * 8 + 2 * p + 1) * SPATIAL];
                unsigned short h0 = f2bf(v0), h1 = f2bf(v1);
                unsigned short l0 = f2bf(v0 - bf2f(h0)), l1 = f2bf(v1 - bf2f(h1));
                hp[p] = (unsigned)h0 | ((unsigned)h1 << 16);
                lp[p] = (unsigned)l0 | ((unsigned)l1 << 16);
            }
            int4 hv = {(int)hp[0], (int)hp[1], (int)hp[2], (int)hp[3]};
            int4 lv = {(int)lp[0], (int)lp[1], (int)lp[2], (int)lp[3]};
            int idx = cl * 16 + (g ^ (cl & 15));
            Ah4[idx] = hv; Al4[idx] = lv;
        }
    }
    __syncthreads();

    const int wrow = (w >> 1) * 64;
    const int wcol = (w & 1) * 64;
    const int l15 = lane & 15;
    const int lg = lane >> 4;

    float b1[16], b2[16];
    int i1[16];
#pragma unroll
    for (int i = 0; i < 16; i++) { b1[i] = FINF; b2[i] = FINF; i1[i] = 0; }

    for (int ct = 0; ct < 8; ct++) {
        // write prefetched B tile to LDS (swizzled)
#pragma unroll
        for (int gi = 0; gi < 8; gi++) {
            int idx = cl * 16 + ((h * 8 + gi) ^ (cl & 15));
            Bh4[idx] = pbh[gi]; Bl4[idx] = pbl[gi];
        }
        __syncthreads();

        // prefetch next tile
        if (ct < 7) {
            const int4* sh = reinterpret_cast<const int4*>(Ehi + (size_t)((ct + 1) * 128 + cl) * CDIM);
            const int4* sl = reinterpret_cast<const int4*>(Elo + (size_t)((ct + 1) * 128 + cl) * CDIM);
#pragma unroll
            for (int gi = 0; gi < 8; gi++) { pbh[gi] = sh[h * 8 + gi]; pbl[gi] = sl[h * 8 + gi]; }
        }

        f32x4 acc[4][4];
#pragma unroll
        for (int m = 0; m < 4; m++)
#pragma unroll
            for (int n = 0; n < 4; n++) acc[m][n] = (f32x4){0.f, 0.f, 0.f, 0.f};

        const short8* Ahs = reinterpret_cast<const short8*>(Ah4);
        const short8* Als = reinterpret_cast<const short8*>(Al4);
        const short8* Bhs = reinterpret_cast<const short8*>(Bh4);
        const short8* Bls = reinterpret_cast<const short8*>(Bl4);

#pragma unroll
        for (int seg = 0; seg < 3; seg++) {
            const short8* As = (seg == 1) ? Als : Ahs;
            const short8* Bs = (seg == 2) ? Bls : Bhs;
#pragma unroll
            for (int kk = 0; kk < 4; kk++) {
                int phys = (kk * 4 + lg) ^ l15;
                short8 av[4], bv[4];
#pragma unroll
                for (int m = 0; m < 4; m++) av[m] = As[(wrow + m * 16 + l15) * 16 + phys];
#pragma unroll
                for (int n = 0; n < 4; n++) bv[n] = Bs[(wcol + n * 16 + l15) * 16 + phys];
#pragma unroll
                for (int m = 0; m < 4; m++)
#pragma unroll
                    for (int n = 0; n < 4; n++)
                        acc[m][n] = __builtin_amdgcn_mfma_f32_16x16x32_bf16(av[m], bv[n], acc[m][n], 0, 0, 0);
            }
        }

        // epilogue: s = ||e||^2 - 2*dot ; track top1(val,idx) + top2(val)
#pragma unroll
        for (int n = 0; n < 4; n++) {
            int col = ct * 128 + wcol + n * 16 + l15;
            float ev = esq[col];
#pragma unroll
            for (int m = 0; m < 4; m++)
#pragma unroll
                for (int r = 0; r < 4; r++) {
                    float sv = fmaf(-2.f, acc[m][n][r], ev);
                    int slot = m * 4 + r;
                    bool c = sv < b1[slot];
                    b2[slot] = fminf(fmaxf(sv, b1[slot]), b2[slot]);   // med3
                    b1[slot] = fminf(sv, b1[slot]);
                    i1[slot] = c ? col : i1[slot];
                }
        }
        __syncthreads();
    }

    // butterfly merge across the 16 col-lanes
#pragma unroll
    for (int j = 1; j < 16; j <<= 1) {
#pragma unroll
        for (int slot = 0; slot < 16; slot++) {
            float ob1 = __shfl_xor(b1[slot], j);
            float ob2 = __shfl_xor(b2[slot], j);
            int   oi  = __shfl_xor(i1[slot], j);
            bool take = (ob1 < b1[slot]) || (ob1 == b1[slot] && oi < i1[slot]);
            float nb2 = fminf(fmaxf(b1[slot], ob1), fminf(b2[slot], ob2));
            b1[slot] = take ? ob1 : b1[slot];
            i1[slot] = take ? oi : i1[slot];
            b2[slot] = nb2;
        }
    }

    if (l15 == 0) {
#pragma unroll
        for (int m = 0; m < 4; m++)
#pragma unroll
            for (int r = 0; r < 4; r++) {
                int rloc = wrow + m * 16 + lg * 4 + r;
                mb1[w & 1][rloc] = b1[m * 4 + r];
                mb2[w & 1][rloc] = b2[m * 4 + r];
                mi1[w & 1][rloc] = i1[m * 4 + r];
            }
    }
    __syncthreads();

    if (tid < SBM) {
        float b1a = mb1[0][tid], b2a = mb2[0][tid];
        float b1b = mb1[1][tid], b2b = mb2[1][tid];
        int i1a = mi1[0][tid], i1b = mi1[1][tid];
        bool take = (b1b < b1a) || (b1b == b1a && i1b < i1a);
        float fb1 = take ? b1b : b1a;
        int   fi1 = take ? i1b : i1a;
        float fb2 = fminf(fmaxf(b1a, b1b), fminf(b2a, b2b));
        int row = row0 + tid;
        idx_ws[row] = fi1;
        if (fb2 - fb1 < MARGIN) {
            int p = atomicAdd(flag_cnt, 1);
            if (p < CAP) flag_list[p] = row;
        }
    }
}

// ---- refine: exact fp32 full rescan of flagged rows -------------------------
__global__ __launch_bounds__(128) void refine_kernel(const float* __restrict__ in,
                                                     const float* __restrict__ emb,
                                                     const float* __restrict__ esq,
                                                     const int* __restrict__ flag_list,
                                                     const int* __restrict__ flag_cnt,
                                                     int* __restrict__ idx_ws) {
    int n = *flag_cnt; if (n > CAP) n = CAP;
    if ((int)blockIdx.x >= n) return;
    __shared__ float xrow[CDIM];
    __shared__ float Ech[CDIM * 129];   // transposed [c][code] with pad
    __shared__ float rv[128];
    __shared__ int   ri[128];

    const int t = threadIdx.x;
    const int row = flag_list[blockIdx.x];
    const int b = row >> 15, s = row & (SPATIAL - 1);
    xrow[t] = in[((size_t)b * CDIM + t) * SPATIAL + s];
    __syncthreads();

    float best = FINF; int bi = 0;
    for (int ch = 0; ch < 8; ch++) {
        const float4* src = reinterpret_cast<const float4*>(emb + (size_t)ch * 128 * CDIM);
#pragma unroll 4
        for (int i = t; i < 128 * 32; i += 128) {     // i = code*32 + c4
            float4 v = src[i];
            int code = i >> 5, c4 = (i & 31) * 4;
            Ech[(c4 + 0) * 129 + code] = v.x;
            Ech[(c4 + 1) * 129 + code] = v.y;
            Ech[(c4 + 2) * 129 + code] = v.z;
            Ech[(c4 + 3) * 129 + code] = v.w;
        }
        __syncthreads();
        int k = ch * 128 + t;
        float dot = 0.f;
#pragma unroll 16
        for (int c = 0; c < CDIM; c++) dot = fmaf(xrow[c], Ech[c * 129 + t], dot);
        float d = fmaf(-2.f, dot, esq[k]);
        if (d < best) { best = d; bi = k; }           // k increasing -> first occurrence
        __syncthreads();
    }
    rv[t] = best; ri[t] = bi;
    __syncthreads();
#pragma unroll
    for (int off = 64; off > 0; off >>= 1) {
        if (t < off) {
            bool take = (rv[t + off] < rv[t]) || (rv[t + off] == rv[t] && ri[t + off] < ri[t]);
            if (take) { rv[t] = rv[t + off]; ri[t] = ri[t + off]; }
        }
        __syncthreads();
    }
    if (t == 0) idx_ws[row] = ri[0];
}

// ---- emit: quantized (channel-first), idx as float, loss partials -----------
__global__ __launch_bounds__(256) void emit_kernel(const float* __restrict__ in,
                                                   const float* __restrict__ emb,
                                                   const int* __restrict__ idx_ws,
                                                   float* __restrict__ out,
                                                   float* __restrict__ partial) {
    __shared__ float red[256];
    const int t = threadIdx.x;
    const int r = blockIdx.x * 256 + t;
    const int b = r >> 15, s = r & (SPATIAL - 1);
    const int k = idx_ws[r];
    out[IDX_OFF + r] = (float)k;

    const float* eb = emb + (size_t)k * CDIM;
    const float* xin = in + (size_t)b * CDIM * SPATIAL + s;
    float* qout = out + (size_t)b * CDIM * SPATIAL + s;
    float lsum = 0.f;
#pragma unroll
    for (int i = 0; i < CDIM / 4; i++) {
        float q0 = eb[4 * i + 0], q1 = eb[4 * i + 1];
        float q2 = eb[4 * i + 2], q3 = eb[4 * i + 3];
        float x0 = xin[(size_t)(4 * i + 0) * SPATIAL];
        float x1 = xin[(size_t)(4 * i + 1) * SPATIAL];
        float x2 = xin[(size_t)(4 * i + 2) * SPATIAL];
        float x3 = xin[(size_t)(4 * i + 3) * SPATIAL];
        float d0 = q0 - x0, d1 = q1 - x1, d2 = q2 - x2, d3 = q3 - x3;
        lsum = fmaf(d0, d0, lsum); lsum = fmaf(d1, d1, lsum);
        lsum = fmaf(d2, d2, lsum); lsum = fmaf(d3, d3, lsum);
        qout[(size_t)(4 * i + 0) * SPATIAL] = q0;
        qout[(size_t)(4 * i + 1) * SPATIAL] = q1;
        qout[(size_t)(4 * i + 2) * SPATIAL] = q2;
        qout[(size_t)(4 * i + 3) * SPATIAL] = q3;
    }
    red[t] = lsum;
    __syncthreads();
#pragma unroll
    for (int off = 128; off > 0; off >>= 1) {
        if (t < off) red[t] += red[t + off];
        __syncthreads();
    }
    if (t == 0) partial[blockIdx.x] = red[0];
}

__global__ __launch_bounds__(512) void finalize_kernel(const float* __restrict__ partial,
                                                       float* __restrict__ out) {
    __shared__ float red[512];
    int t = threadIdx.x;
    red[t] = partial[t];
    __syncthreads();
#pragma unroll
    for (int off = 256; off > 0; off >>= 1) {
        if (t < off) red[t] += red[t + off];
        __syncthreads();
    }
    if (t == 0) out[LOSS_OFF] = 0.25f * red[0] / (float)Q_SIZE;
}

extern "C" void kernel_launch(void* const* d_in, const int* in_sizes, int n_in,
                              void* d_out, int out_size, void* d_ws, size_t ws_size,
                              hipStream_t stream) {
    const float* in = (const float*)d_in[0];
    const float* emb = (const float*)d_in[1];
    float* out = (float*)d_out;

    float* esq = (float*)d_ws;                                  // 1024 f32
    unsigned short* Ehi = (unsigned short*)(esq + KCODES);      // 131072 u16
    unsigned short* Elo = Ehi + KCODES * CDIM;                  // 131072 u16
    int* idx_ws = (int*)(Elo + KCODES * CDIM);                  // 131072 i32
    int* flag_list = idx_ws + NROWS;                            // CAP i32
    int* flag_cnt = flag_list + CAP;                            // 1 i32
    float* partial = (float*)(flag_cnt + 1);                    // 512 f32

    hipMemsetAsync(flag_cnt, 0, sizeof(int), stream);
    hipMemsetAsync(out + ESUM_OFF, 0, 256 * sizeof(float), stream);
    hipMemcpyAsync(out + EMB_OFF, emb, (size_t)KCODES * CDIM * sizeof(float),
                   hipMemcpyDeviceToDevice, stream);

    prep_kernel<<<KCODES / 256, 256, 0, stream>>>(emb, Ehi, Elo, esq);
    score_kernel<<<SCORE_BLOCKS, 256, 0, stream>>>(in, Ehi, Elo, esq, idx_ws, flag_list, flag_cnt);
    refine_kernel<<<CAP, 128, 0, stream>>>(in, emb, esq, flag_list, flag_cnt, idx_ws);
    emit_kernel<<<NROWS / 256, 256, 0, stream>>>(in, emb, idx_ws, out, partial);
    finalize_kernel<<<1, 512, 0, stream>>>(partial, out);
}

// Round 3
// 210.339 us; speedup vs baseline: 3.7148x; 1.9086x over previous
//
#include <hip/hip_runtime.h>

// Problem geometry (fixed by the reference)
#define SPATIAL 32768            // D*H*W
#define NB 4
#define CDIM 128
#define KCODES 1024
#define NROWS (NB * SPATIAL)     // 131072

// Output layout in d_out (all float32, concatenated in return order)
#define Q_SIZE (NB * CDIM * SPATIAL)     // 16777216
#define LOSS_OFF Q_SIZE
#define IDX_OFF (Q_SIZE + 1)
#define ESUM_OFF (IDX_OFF + NROWS)
#define EMB_OFF (ESUM_OFF + 256)

#define MARGIN 0.05f
#define CAP 4096
#define FINF 3.4e38f

typedef short short8 __attribute__((ext_vector_type(8)));
typedef float f32x4 __attribute__((ext_vector_type(4)));

static __device__ __forceinline__ unsigned short f2bf(float x) {
    unsigned u = __float_as_uint(x);
    unsigned r = (u + 0x7fffu + ((u >> 16) & 1u)) >> 16;   // RN-even
    return (unsigned short)r;
}
static __device__ __forceinline__ float bf2f(unsigned short h) {
    return __uint_as_float(((unsigned)h) << 16);
}

static __device__ __forceinline__ void gload16(const uint4* g, uint4* l) {
    __builtin_amdgcn_global_load_lds(
        (const __attribute__((address_space(1))) unsigned int*)g,
        (__attribute__((address_space(3))) unsigned int*)l, 16, 0, 0);
}

// ---- prep: emb -> packed, pre-swizzled bf16 hi/lo B tiles + exact ||e||^2 ---
// Bpk layout (uint4 granules of 8 bf16): [(ct*2 + hl)*128 + code][ g ^ (code&15) ]
__global__ __launch_bounds__(256) void prep_kernel(const float* __restrict__ emb,
                                                   uint4* __restrict__ Bpk,
                                                   float* __restrict__ esq) {
    int k = blockIdx.x * 256 + threadIdx.x;
    if (k >= KCODES) return;
    int ct = k >> 7, cl = k & 127;
    const float* e = emb + (size_t)k * CDIM;
    uint4* bh = Bpk + ((size_t)(ct * 2 + 0) * 128 + cl) * 16;
    uint4* bl = Bpk + ((size_t)(ct * 2 + 1) * 128 + cl) * 16;
    float s = 0.f;
#pragma unroll
    for (int g = 0; g < 16; g++) {
        unsigned hp[4], lp[4];
#pragma unroll
        for (int p = 0; p < 4; p++) {
            float v0 = e[g * 8 + 2 * p + 0];
            float v1 = e[g * 8 + 2 * p + 1];
            unsigned short h0 = f2bf(v0), h1 = f2bf(v1);
            unsigned short l0 = f2bf(v0 - bf2f(h0)), l1 = f2bf(v1 - bf2f(h1));
            hp[p] = (unsigned)h0 | ((unsigned)h1 << 16);
            lp[p] = (unsigned)l0 | ((unsigned)l1 << 16);
            s = fmaf(v0, v0, s);
            s = fmaf(v1, v1, s);
        }
        int gp = g ^ (cl & 15);
        bh[gp] = make_uint4(hp[0], hp[1], hp[2], hp[3]);
        bl[gp] = make_uint4(lp[0], lp[1], lp[2], lp[3]);
    }
    esq[k] = s;
}

// ---- scoring: A in registers, B-only LDS via global_load_lds ----------------
__global__ __launch_bounds__(256, 2) void score_kernel(const float* __restrict__ in,
                                                       const uint4* __restrict__ Bpk,
                                                       const float* __restrict__ esq,
                                                       int* __restrict__ idx_ws,
                                                       int* __restrict__ flag_list,
                                                       int* __restrict__ flag_cnt) {
    __shared__ uint4 BB[2 * 128 * 16];   // 64 KB: one B tile (128 codes, hi+lo)

    const int tid = threadIdx.x;
    const int lane = tid & 63;
    const int w = tid >> 6;              // wave 0..3, owns rows w*32..w*32+31
    const int l15 = lane & 15;
    const int lg = lane >> 4;
    const int row0 = blockIdx.x * 128;
    const int b = row0 >> 15;
    const int sbase = (row0 & (SPATIAL - 1)) + w * 32;

    // ---- A fragments in registers: hi+lo bf16, all K=128, held throughout
    short8 Ah[8], Al[8];                 // index [kk*2 + m]
    {
        const float* xb = in + (size_t)b * CDIM * SPATIAL;
#pragma unroll
        for (int kk = 0; kk < 4; kk++)
#pragma unroll
            for (int m = 0; m < 2; m++) {
                int srow = sbase + m * 16 + l15;
                unsigned hh[4], ll[4];
#pragma unroll
                for (int p = 0; p < 4; p++) {
                    int c0 = kk * 32 + lg * 8 + 2 * p;
                    float v0 = xb[(size_t)(c0 + 0) * SPATIAL + srow];
                    float v1 = xb[(size_t)(c0 + 1) * SPATIAL + srow];
                    unsigned short h0 = f2bf(v0), h1 = f2bf(v1);
                    unsigned short l0 = f2bf(v0 - bf2f(h0)), l1 = f2bf(v1 - bf2f(h1));
                    hh[p] = (unsigned)h0 | ((unsigned)h1 << 16);
                    ll[p] = (unsigned)l0 | ((unsigned)l1 << 16);
                }
                union { unsigned u[4]; short8 s; } ch, cl2;
#pragma unroll
                for (int p = 0; p < 4; p++) { ch.u[p] = hh[p]; cl2.u[p] = ll[p]; }
                Ah[kk * 2 + m] = ch.s;
                Al[kk * 2 + m] = cl2.s;
            }
    }

    float b1[8], b2[8];
    int i1[8];
#pragma unroll
    for (int i = 0; i < 8; i++) { b1[i] = FINF; b2[i] = FINF; i1[i] = 0; }

    const short8* BBs = reinterpret_cast<const short8*>(BB);

    for (int ct = 0; ct < 8; ct++) {
        // stage B tile (64 KB) straight into LDS, no VGPRs
        const uint4* src = Bpk + (size_t)ct * 4096;
#pragma unroll
        for (int i = 0; i < 16; i++) {
            int ub = i * 256 + w * 64;
            gload16(src + ub + lane, &BB[ub]);
        }
        __syncthreads();   // drains vmcnt before reads

#pragma unroll
        for (int half = 0; half < 2; half++) {
            f32x4 acc[2][4];
#pragma unroll
            for (int m = 0; m < 2; m++)
#pragma unroll
                for (int n = 0; n < 4; n++) acc[m][n] = (f32x4){0.f, 0.f, 0.f, 0.f};

#pragma unroll
            for (int kk = 0; kk < 4; kk++) {
                int phys = (kk * 4 + lg) ^ l15;
                short8 bh[4], bl[4];
#pragma unroll
                for (int n = 0; n < 4; n++) {
                    int un = (half * 64 + n * 16 + l15) * 16 + phys;
                    bh[n] = BBs[un];
                    bl[n] = BBs[2048 + un];
                }
#pragma unroll
                for (int m = 0; m < 2; m++)
#pragma unroll
                    for (int n = 0; n < 4; n++)
                        acc[m][n] = __builtin_amdgcn_mfma_f32_16x16x32_bf16(Ah[kk * 2 + m], bh[n], acc[m][n], 0, 0, 0);
#pragma unroll
                for (int m = 0; m < 2; m++)
#pragma unroll
                    for (int n = 0; n < 4; n++)
                        acc[m][n] = __builtin_amdgcn_mfma_f32_16x16x32_bf16(Al[kk * 2 + m], bh[n], acc[m][n], 0, 0, 0);
#pragma unroll
                for (int m = 0; m < 2; m++)
#pragma unroll
                    for (int n = 0; n < 4; n++)
                        acc[m][n] = __builtin_amdgcn_mfma_f32_16x16x32_bf16(Ah[kk * 2 + m], bl[n], acc[m][n], 0, 0, 0);
            }

            // epilogue: s = ||e||^2 - 2*dot ; top1(val,idx) + top2(val)
#pragma unroll
            for (int n = 0; n < 4; n++) {
                int col = ct * 128 + half * 64 + n * 16 + l15;
                float ev = esq[col];
#pragma unroll
                for (int m = 0; m < 2; m++)
#pragma unroll
                    for (int r = 0; r < 4; r++) {
                        float sv = fmaf(-2.f, acc[m][n][r], ev);
                        int slot = m * 4 + r;
                        bool c = sv < b1[slot];
                        b2[slot] = fminf(fmaxf(sv, b1[slot]), b2[slot]);   // med3
                        b1[slot] = fminf(sv, b1[slot]);
                        i1[slot] = c ? col : i1[slot];
                    }
            }
        }
        __syncthreads();   // before next tile overwrites BB
    }

    // butterfly merge across the 16 col-lanes (stays within l15 group)
#pragma unroll
    for (int j = 1; j < 16; j <<= 1) {
#pragma unroll
        for (int slot = 0; slot < 8; slot++) {
            float ob1 = __shfl_xor(b1[slot], j);
            float ob2 = __shfl_xor(b2[slot], j);
            int   oi  = __shfl_xor(i1[slot], j);
            bool take = (ob1 < b1[slot]) || (ob1 == b1[slot] && oi < i1[slot]);
            float nb2 = fminf(fmaxf(b1[slot], ob1), fminf(b2[slot], ob2));
            b1[slot] = take ? ob1 : b1[slot];
            i1[slot] = take ? oi : i1[slot];
            b2[slot] = nb2;
        }
    }

    if (l15 == 0) {
#pragma unroll
        for (int m = 0; m < 2; m++)
#pragma unroll
            for (int r = 0; r < 4; r++) {
                int slot = m * 4 + r;
                int row = row0 + w * 32 + m * 16 + lg * 4 + r;
                idx_ws[row] = i1[slot];
                if (b2[slot] - b1[slot] < MARGIN) {
                    int p = atomicAdd(flag_cnt, 1);
                    if (p < CAP) flag_list[p] = row;
                }
            }
    }
}

// ---- refine: exact fp32 full rescan of flagged rows -------------------------
__global__ __launch_bounds__(128) void refine_kernel(const float* __restrict__ in,
                                                     const float* __restrict__ emb,
                                                     const float* __restrict__ esq,
                                                     const int* __restrict__ flag_list,
                                                     const int* __restrict__ flag_cnt,
                                                     int* __restrict__ idx_ws) {
    int n = *flag_cnt; if (n > CAP) n = CAP;
    if ((int)blockIdx.x >= n) return;
    __shared__ float xrow[CDIM];
    __shared__ float Ech[CDIM * 129];
    __shared__ float rv[128];
    __shared__ int   ri[128];

    const int t = threadIdx.x;
    const int row = flag_list[blockIdx.x];
    const int b = row >> 15, s = row & (SPATIAL - 1);
    xrow[t] = in[((size_t)b * CDIM + t) * SPATIAL + s];
    __syncthreads();

    float best = FINF; int bi = 0;
    for (int ch = 0; ch < 8; ch++) {
        const float4* src = reinterpret_cast<const float4*>(emb + (size_t)ch * 128 * CDIM);
#pragma unroll 4
        for (int i = t; i < 128 * 32; i += 128) {
            float4 v = src[i];
            int code = i >> 5, c4 = (i & 31) * 4;
            Ech[(c4 + 0) * 129 + code] = v.x;
            Ech[(c4 + 1) * 129 + code] = v.y;
            Ech[(c4 + 2) * 129 + code] = v.z;
            Ech[(c4 + 3) * 129 + code] = v.w;
        }
        __syncthreads();
        int k = ch * 128 + t;
        float dot = 0.f;
#pragma unroll 16
        for (int c = 0; c < CDIM; c++) dot = fmaf(xrow[c], Ech[c * 129 + t], dot);
        float d = fmaf(-2.f, dot, esq[k]);
        if (d < best) { best = d; bi = k; }
        __syncthreads();
    }
    rv[t] = best; ri[t] = bi;
    __syncthreads();
#pragma unroll
    for (int off = 64; off > 0; off >>= 1) {
        if (t < off) {
            bool take = (rv[t + off] < rv[t]) || (rv[t + off] == rv[t] && ri[t + off] < ri[t]);
            if (take) { rv[t] = rv[t + off]; ri[t] = ri[t + off]; }
        }
        __syncthreads();
    }
    if (t == 0) idx_ws[row] = ri[0];
}

// ---- emit: quantized (channel-first), idx as float, loss partials -----------
__global__ __launch_bounds__(256) void emit_kernel(const float* __restrict__ in,
                                                   const float* __restrict__ emb,
                                                   const int* __restrict__ idx_ws,
                                                   float* __restrict__ out,
                                                   float* __restrict__ partial) {
    __shared__ float red[256];
    const int t = threadIdx.x;
    const int r = blockIdx.x * 256 + t;
    const int b = r >> 15, s = r & (SPATIAL - 1);
    const int k = idx_ws[r];
    out[IDX_OFF + r] = (float)k;

    const float* eb = emb + (size_t)k * CDIM;
    const float* xin = in + (size_t)b * CDIM * SPATIAL + s;
    float* qout = out + (size_t)b * CDIM * SPATIAL + s;
    float lsum = 0.f;
#pragma unroll
    for (int i = 0; i < CDIM / 4; i++) {
        float q0 = eb[4 * i + 0], q1 = eb[4 * i + 1];
        float q2 = eb[4 * i + 2], q3 = eb[4 * i + 3];
        float x0 = xin[(size_t)(4 * i + 0) * SPATIAL];
        float x1 = xin[(size_t)(4 * i + 1) * SPATIAL];
        float x2 = xin[(size_t)(4 * i + 2) * SPATIAL];
        float x3 = xin[(size_t)(4 * i + 3) * SPATIAL];
        float d0 = q0 - x0, d1 = q1 - x1, d2 = q2 - x2, d3 = q3 - x3;
        lsum = fmaf(d0, d0, lsum); lsum = fmaf(d1, d1, lsum);
        lsum = fmaf(d2, d2, lsum); lsum = fmaf(d3, d3, lsum);
        qout[(size_t)(4 * i + 0) * SPATIAL] = q0;
        qout[(size_t)(4 * i + 1) * SPATIAL] = q1;
        qout[(size_t)(4 * i + 2) * SPATIAL] = q2;
        qout[(size_t)(4 * i + 3) * SPATIAL] = q3;
    }
    red[t] = lsum;
    __syncthreads();
#pragma unroll
    for (int off = 128; off > 0; off >>= 1) {
        if (t < off) red[t] += red[t + off];
        __syncthreads();
    }
    if (t == 0) partial[blockIdx.x] = red[0];
}

__global__ __launch_bounds__(512) void finalize_kernel(const float* __restrict__ partial,
                                                       float* __restrict__ out) {
    __shared__ float red[512];
    int t = threadIdx.x;
    red[t] = partial[t];
    __syncthreads();
#pragma unroll
    for (int off = 256; off > 0; off >>= 1) {
        if (t < off) red[t] += red[t + off];
        __syncthreads();
    }
    if (t == 0) out[LOSS_OFF] = 0.25f * red[0] / (float)Q_SIZE;
}

extern "C" void kernel_launch(void* const* d_in, const int* in_sizes, int n_in,
                              void* d_out, int out_size, void* d_ws, size_t ws_size,
                              hipStream_t stream) {
    const float* in = (const float*)d_in[0];
    const float* emb = (const float*)d_in[1];
    float* out = (float*)d_out;

    float* esq = (float*)d_ws;                                  // 1024 f32
    uint4* Bpk = (uint4*)(esq + KCODES);                        // 32768 uint4 (512 KB)
    int* idx_ws = (int*)(Bpk + 8 * 4096);                       // 131072 i32
    int* flag_list = idx_ws + NROWS;                            // CAP i32
    int* flag_cnt = flag_list + CAP;                            // 1 i32
    float* partial = (float*)(flag_cnt + 1);                    // 512 f32

    hipMemsetAsync(flag_cnt, 0, sizeof(int), stream);
    hipMemsetAsync(out + ESUM_OFF, 0, 256 * sizeof(float), stream);
    hipMemcpyAsync(out + EMB_OFF, emb, (size_t)KCODES * CDIM * sizeof(float),
                   hipMemcpyDeviceToDevice, stream);

    prep_kernel<<<KCODES / 256, 256, 0, stream>>>(emb, Bpk, esq);
    score_kernel<<<NROWS / 128, 256, 0, stream>>>(in, Bpk, esq, idx_ws, flag_list, flag_cnt);
    refine_kernel<<<CAP, 128, 0, stream>>>(in, emb, esq, flag_list, flag_cnt, idx_ws);
    emit_kernel<<<NROWS / 256, 256, 0, stream>>>(in, emb, idx_ws, out, partial);
    finalize_kernel<<<1, 512, 0, stream>>>(partial, out);
}

// Round 4
// 209.988 us; speedup vs baseline: 3.7210x; 1.0017x over previous
//
#include <hip/hip_runtime.h>

// Problem geometry (fixed by the reference)
#define SPATIAL 32768            // D*H*W
#define NB 4
#define CDIM 128
#define KCODES 1024
#define NROWS (NB * SPATIAL)     // 131072

// Output layout in d_out (all float32, concatenated in return order)
#define Q_SIZE (NB * CDIM * SPATIAL)     // 16777216
#define LOSS_OFF Q_SIZE
#define IDX_OFF (Q_SIZE + 1)
#define ESUM_OFF (IDX_OFF + NROWS)
#define EMB_OFF (ESUM_OFF + 256)

#define TCODES 64                // codes per tile
#define NT (KCODES / TCODES)     // 16 tiles
#define MARGIN 0.05f
#define CAP 4096
#define FINF 3.4e38f

typedef short short8 __attribute__((ext_vector_type(8)));
typedef float f32x4 __attribute__((ext_vector_type(4)));

static __device__ __forceinline__ unsigned short f2bf(float x) {
    unsigned u = __float_as_uint(x);
    unsigned r = (u + 0x7fffu + ((u >> 16) & 1u)) >> 16;   // RN-even
    return (unsigned short)r;
}
static __device__ __forceinline__ float bf2f(unsigned short h) {
    return __uint_as_float(((unsigned)h) << 16);
}

static __device__ __forceinline__ void gload16(const uint4* g, uint4* l) {
    __builtin_amdgcn_global_load_lds(
        (const __attribute__((address_space(1))) unsigned int*)g,
        (__attribute__((address_space(3))) unsigned int*)l, 16, 0, 0);
}

// ---- prep: emb -> packed, pre-swizzled bf16 hi/lo tiles of 64 codes ---------
// Bpk (uint4 granules of 8 bf16): [((t*2 + hl)*64 + cl)*16 + (g ^ (cl&15))]
__global__ __launch_bounds__(256) void prep_kernel(const float* __restrict__ emb,
                                                   uint4* __restrict__ Bpk,
                                                   float* __restrict__ esq) {
    int k = blockIdx.x * 256 + threadIdx.x;
    if (k >= KCODES) return;
    int t = k >> 6, cl = k & 63;
    const float* e = emb + (size_t)k * CDIM;
    uint4* bh = Bpk + ((size_t)(t * 2 + 0) * TCODES + cl) * 16;
    uint4* bl = Bpk + ((size_t)(t * 2 + 1) * TCODES + cl) * 16;
    float s = 0.f;
#pragma unroll
    for (int g = 0; g < 16; g++) {
        unsigned hp[4], lp[4];
#pragma unroll
        for (int p = 0; p < 4; p++) {
            float v0 = e[g * 8 + 2 * p + 0];
            float v1 = e[g * 8 + 2 * p + 1];
            unsigned short h0 = f2bf(v0), h1 = f2bf(v1);
            unsigned short l0 = f2bf(v0 - bf2f(h0)), l1 = f2bf(v1 - bf2f(h1));
            hp[p] = (unsigned)h0 | ((unsigned)h1 << 16);
            lp[p] = (unsigned)l0 | ((unsigned)l1 << 16);
            s = fmaf(v0, v0, s);
            s = fmaf(v1, v1, s);
        }
        int gp = g ^ (cl & 15);
        bh[gp] = make_uint4(hp[0], hp[1], hp[2], hp[3]);
        bl[gp] = make_uint4(lp[0], lp[1], lp[2], lp[3]);
    }
    esq[k] = s;
}

// ---- scoring + fused emit: A in regs, double-buffered B tiles ---------------
__global__ __launch_bounds__(256, 2) void score_kernel(const float* __restrict__ in,
                                                       const uint4* __restrict__ Bpk,
                                                       const float* __restrict__ esq,
                                                       const float* __restrict__ emb,
                                                       float* __restrict__ out,
                                                       float* __restrict__ c_row,
                                                       int* __restrict__ flag_list,
                                                       int* __restrict__ flag_cnt) {
    __shared__ uint4 BB[2][2 * TCODES * 16];   // 2 x 32 KB (hi then lo, 1024 granules each)
    __shared__ float b1L[128];
    __shared__ int   i1L[128];
    __shared__ float xsqL[128];

    const int tid = threadIdx.x;
    const int lane = tid & 63;
    const int w = tid >> 6;              // wave 0..3, owns rows w*32..w*32+31
    const int l15 = lane & 15;
    const int lg = lane >> 4;
    const int row0 = blockIdx.x * 128;
    const int b = row0 >> 15;
    const int sbase = (row0 & (SPATIAL - 1)) + w * 32;

#define STAGE(tt, bb)                                                     \
    do {                                                                  \
        const uint4* src_ = Bpk + (size_t)(tt) * 2048;                    \
        _Pragma("unroll")                                                 \
        for (int i_ = 0; i_ < 8; i_++) {                                  \
            int ub_ = i_ * 256 + w * 64;                                  \
            gload16(src_ + ub_ + lane, &BB[bb][ub_]);                     \
        }                                                                 \
    } while (0)

    STAGE(0, 0);   // tile-0 DMA overlaps the A-load below

    // ---- A fragments in registers: hi+lo bf16, all K=128; exact ||x||^2
    short8 Ah[8], Al[8];                 // index [kk*2 + m]
    float xsq[2] = {0.f, 0.f};
    {
        const float* xb = in + (size_t)b * CDIM * SPATIAL;
#pragma unroll
        for (int kk = 0; kk < 4; kk++)
#pragma unroll
            for (int m = 0; m < 2; m++) {
                int srow = sbase + m * 16 + l15;
                unsigned hh[4], ll[4];
#pragma unroll
                for (int p = 0; p < 4; p++) {
                    int c0 = kk * 32 + lg * 8 + 2 * p;
                    float v0 = xb[(size_t)(c0 + 0) * SPATIAL + srow];
                    float v1 = xb[(size_t)(c0 + 1) * SPATIAL + srow];
                    unsigned short h0 = f2bf(v0), h1 = f2bf(v1);
                    unsigned short l0 = f2bf(v0 - bf2f(h0)), l1 = f2bf(v1 - bf2f(h1));
                    hh[p] = (unsigned)h0 | ((unsigned)h1 << 16);
                    ll[p] = (unsigned)l0 | ((unsigned)l1 << 16);
                    xsq[m] = fmaf(v0, v0, xsq[m]);
                    xsq[m] = fmaf(v1, v1, xsq[m]);
                }
                union { unsigned u[4]; short8 s; } ch, cl2;
#pragma unroll
                for (int p = 0; p < 4; p++) { ch.u[p] = hh[p]; cl2.u[p] = ll[p]; }
                Ah[kk * 2 + m] = ch.s;
                Al[kk * 2 + m] = cl2.s;
            }
    }
    // reduce ||x||^2 over the 4 lg channel-groups (lanes l15, 16+l15, 32+l15, 48+l15)
#pragma unroll
    for (int m = 0; m < 2; m++) {
        xsq[m] += __shfl_xor(xsq[m], 16);
        xsq[m] += __shfl_xor(xsq[m], 32);
    }
    if (lg == 0) {
        xsqL[w * 32 + l15] = xsq[0];
        xsqL[w * 32 + 16 + l15] = xsq[1];
    }

    float b1[8], b2[8];
    int i1[8];
#pragma unroll
    for (int i = 0; i < 8; i++) { b1[i] = FINF; b2[i] = FINF; i1[i] = 0; }

    __syncthreads();   // tile-0 DMA drained (vmcnt 0 at barrier) + xsqL visible

    for (int t = 0; t < NT; t++) {
        if (t + 1 < NT) STAGE(t + 1, (t + 1) & 1);      // issue next-tile DMA first

        const short8* Bs = reinterpret_cast<const short8*>(BB[t & 1]);
        f32x4 acc[2][4];
#pragma unroll
        for (int m = 0; m < 2; m++)
#pragma unroll
            for (int n = 0; n < 4; n++) acc[m][n] = (f32x4){0.f, 0.f, 0.f, 0.f};

#pragma unroll
        for (int kk = 0; kk < 4; kk++) {
            int phys = (kk * 4 + lg) ^ l15;
            short8 bh[4], bl[4];
#pragma unroll
            for (int n = 0; n < 4; n++) {
                int un = (n * 16 + l15) * 16 + phys;
                bh[n] = Bs[un];
                bl[n] = Bs[1024 + un];
            }
#pragma unroll
            for (int m = 0; m < 2; m++)
#pragma unroll
                for (int n = 0; n < 4; n++)
                    acc[m][n] = __builtin_amdgcn_mfma_f32_16x16x32_bf16(Ah[kk * 2 + m], bh[n], acc[m][n], 0, 0, 0);
#pragma unroll
            for (int m = 0; m < 2; m++)
#pragma unroll
                for (int n = 0; n < 4; n++)
                    acc[m][n] = __builtin_amdgcn_mfma_f32_16x16x32_bf16(Al[kk * 2 + m], bh[n], acc[m][n], 0, 0, 0);
#pragma unroll
            for (int m = 0; m < 2; m++)
#pragma unroll
                for (int n = 0; n < 4; n++)
                    acc[m][n] = __builtin_amdgcn_mfma_f32_16x16x32_bf16(Ah[kk * 2 + m], bl[n], acc[m][n], 0, 0, 0);
        }

        // epilogue: s = ||e||^2 - 2*dot ; top1(val,idx) + top2(val)
#pragma unroll
        for (int n = 0; n < 4; n++) {
            int col = t * TCODES + n * 16 + l15;
            float ev = esq[col];
#pragma unroll
            for (int m = 0; m < 2; m++)
#pragma unroll
                for (int r = 0; r < 4; r++) {
                    float sv = fmaf(-2.f, acc[m][n][r], ev);
                    int slot = m * 4 + r;
                    bool c = sv < b1[slot];
                    b2[slot] = fminf(fmaxf(sv, b1[slot]), b2[slot]);   // med3
                    b1[slot] = fminf(sv, b1[slot]);
                    i1[slot] = c ? col : i1[slot];
                }
        }
        __syncthreads();   // tile t reads done; next-tile DMA drained
    }
#undef STAGE

    // butterfly merge across the 16 col-lanes (all lanes end with merged result)
#pragma unroll
    for (int j = 1; j < 16; j <<= 1) {
#pragma unroll
        for (int slot = 0; slot < 8; slot++) {
            float ob1 = __shfl_xor(b1[slot], j);
            float ob2 = __shfl_xor(b2[slot], j);
            int   oi  = __shfl_xor(i1[slot], j);
            bool take = (ob1 < b1[slot]) || (ob1 == b1[slot] && oi < i1[slot]);
            float nb2 = fminf(fmaxf(b1[slot], ob1), fminf(b2[slot], ob2));
            b1[slot] = take ? ob1 : b1[slot];
            i1[slot] = take ? oi : i1[slot];
            b2[slot] = nb2;
        }
    }

    if (l15 == 0) {
#pragma unroll
        for (int m = 0; m < 2; m++)
#pragma unroll
            for (int r = 0; r < 4; r++) {
                int slot = m * 4 + r;
                int rl = w * 32 + m * 16 + lg * 4 + r;
                b1L[rl] = b1[slot];
                i1L[rl] = i1[slot];
                if (b2[slot] - b1[slot] < MARGIN) {
                    int p = atomicAdd(flag_cnt, 1);
                    if (p < CAP) flag_list[p] = row0 + rl;
                }
            }
    }
    __syncthreads();

    // ---- fused emit: idx, per-row loss contribution, quantized (gather emb[k])
    {
        const int rl = w * 32 + (lane & 31);          // local row in block
        const int row = row0 + rl;
        const int sp = (row0 & (SPATIAL - 1)) + rl;   // spatial index
        const int k = i1L[rl];
        const int chalf = lane >> 5;                  // channels chalf*64 .. +63

        if (chalf == 0) {
            out[IDX_OFF + row] = (float)k;
            c_row[row] = b1L[rl] + xsqL[rl];          // ||e||^2 - 2 x.e + ||x||^2
        }
        const float4* ep = reinterpret_cast<const float4*>(emb + (size_t)k * CDIM + chalf * 64);
        float* qout = out + (size_t)b * CDIM * SPATIAL + (size_t)chalf * 64 * SPATIAL + sp;
#pragma unroll
        for (int i = 0; i < 16; i++) {
            float4 v = ep[i];
            qout[(size_t)(4 * i + 0) * SPATIAL] = v.x;
            qout[(size_t)(4 * i + 1) * SPATIAL] = v.y;
            qout[(size_t)(4 * i + 2) * SPATIAL] = v.z;
            qout[(size_t)(4 * i + 3) * SPATIAL] = v.w;
        }
    }
}

// ---- refine: exact fp32 rescan of flagged rows; fixes idx, q row, c_row -----
__global__ __launch_bounds__(128) void refine_kernel(const float* __restrict__ in,
                                                     const float* __restrict__ emb,
                                                     const float* __restrict__ esq,
                                                     const int* __restrict__ flag_list,
                                                     const int* __restrict__ flag_cnt,
                                                     float* __restrict__ out,
                                                     float* __restrict__ c_row) {
    int n = *flag_cnt; if (n > CAP) n = CAP;
    if ((int)blockIdx.x >= n) return;
    __shared__ float xrow[CDIM];
    __shared__ float Ech[CDIM * 129];
    __shared__ float rv[128];
    __shared__ int   ri[128];

    const int t = threadIdx.x;
    const int row = flag_list[blockIdx.x];
    const int b = row >> 15, s = row & (SPATIAL - 1);
    xrow[t] = in[((size_t)b * CDIM + t) * SPATIAL + s];
    __syncthreads();

    float best = FINF; int bi = 0;
    for (int ch = 0; ch < 8; ch++) {
        const float4* src = reinterpret_cast<const float4*>(emb + (size_t)ch * 128 * CDIM);
#pragma unroll 4
        for (int i = t; i < 128 * 32; i += 128) {
            float4 v = src[i];
            int code = i >> 5, c4 = (i & 31) * 4;
            Ech[(c4 + 0) * 129 + code] = v.x;
            Ech[(c4 + 1) * 129 + code] = v.y;
            Ech[(c4 + 2) * 129 + code] = v.z;
            Ech[(c4 + 3) * 129 + code] = v.w;
        }
        __syncthreads();
        int k = ch * 128 + t;
        float dot = 0.f;
#pragma unroll 16
        for (int c = 0; c < CDIM; c++) dot = fmaf(xrow[c], Ech[c * 129 + t], dot);
        float d = fmaf(-2.f, dot, esq[k]);
        if (d < best) { best = d; bi = k; }
        __syncthreads();
    }
    rv[t] = best; ri[t] = bi;
    __syncthreads();
#pragma unroll
    for (int off = 64; off > 0; off >>= 1) {
        if (t < off) {
            bool take = (rv[t + off] < rv[t]) || (rv[t + off] == rv[t] && ri[t + off] < ri[t]);
            if (take) { rv[t] = rv[t + off]; ri[t] = ri[t + off]; }
        }
        __syncthreads();
    }
    const int kbest = ri[0];
    const float dbest = rv[0];
    __syncthreads();
    // exact ||x||^2 reduce
    rv[t] = xrow[t] * xrow[t];
    __syncthreads();
#pragma unroll
    for (int off = 64; off > 0; off >>= 1) {
        if (t < off) rv[t] += rv[t + off];
        __syncthreads();
    }
    if (t == 0) {
        out[IDX_OFF + row] = (float)kbest;
        c_row[row] = dbest + rv[0];
    }
    // rewrite quantized row
    out[(size_t)b * CDIM * SPATIAL + (size_t)t * SPATIAL + s] = emb[(size_t)kbest * CDIM + t];
}

// ---- loss: sum c_row -> scalar ----------------------------------------------
__global__ __launch_bounds__(1024) void loss_kernel(const float* __restrict__ c_row,
                                                    float* __restrict__ out) {
    __shared__ float red[1024];
    const int t = threadIdx.x;
    float s = 0.f;
    const float4* c4 = reinterpret_cast<const float4*>(c_row);
    for (int i = t; i < NROWS / 4; i += 1024) {
        float4 v = c4[i];
        s += (v.x + v.y) + (v.z + v.w);
    }
    red[t] = s;
    __syncthreads();
#pragma unroll
    for (int off = 512; off > 0; off >>= 1) {
        if (t < off) red[t] += red[t + off];
        __syncthreads();
    }
    if (t == 0) out[LOSS_OFF] = 0.25f * red[0] / (float)Q_SIZE;
}

extern "C" void kernel_launch(void* const* d_in, const int* in_sizes, int n_in,
                              void* d_out, int out_size, void* d_ws, size_t ws_size,
                              hipStream_t stream) {
    const float* in = (const float*)d_in[0];
    const float* emb = (const float*)d_in[1];
    float* out = (float*)d_out;

    float* esq = (float*)d_ws;                                  // 1024 f32 (16 KB w/ pad)
    uint4* Bpk = (uint4*)(esq + 4096);                          // 32768 uint4 (512 KB)
    float* c_row = (float*)(Bpk + NT * 2048);                   // 131072 f32 (512 KB)
    int* flag_list = (int*)(c_row + NROWS);                     // CAP i32
    int* flag_cnt = flag_list + CAP;                            // 1 i32

    hipMemsetAsync(flag_cnt, 0, sizeof(int), stream);
    hipMemsetAsync(out + ESUM_OFF, 0, 256 * sizeof(float), stream);
    hipMemcpyAsync(out + EMB_OFF, emb, (size_t)KCODES * CDIM * sizeof(float),
                   hipMemcpyDeviceToDevice, stream);

    prep_kernel<<<KCODES / 256, 256, 0, stream>>>(emb, Bpk, esq);
    score_kernel<<<NROWS / 128, 256, 0, stream>>>(in, Bpk, esq, emb, out, c_row, flag_list, flag_cnt);
    refine_kernel<<<CAP, 128, 0, stream>>>(in, emb, esq, flag_list, flag_cnt, out, c_row);
    loss_kernel<<<1, 1024, 0, stream>>>(c_row, out);
}

// Round 5
// 194.789 us; speedup vs baseline: 4.0114x; 1.0780x over previous
//
#include <hip/hip_runtime.h>

// Problem geometry (fixed by the reference)
#define SPATIAL 32768            // D*H*W
#define NB 4
#define CDIM 128
#define KCODES 1024
#define NROWS (NB * SPATIAL)     // 131072

// Output layout in d_out (all float32, concatenated in return order)
#define Q_SIZE (NB * CDIM * SPATIAL)     // 16777216
#define LOSS_OFF Q_SIZE
#define IDX_OFF (Q_SIZE + 1)
#define ESUM_OFF (IDX_OFF + NROWS)
#define EMB_OFF (ESUM_OFF + 256)

#define TCODES 64                // codes per tile
#define NT (KCODES / TCODES)     // 16 tiles
#define MARGIN 0.06f
#define CAP 4096
#define FINF 3.4e38f
#define LSCALE 1048576.0f        // 2^20 fixed-point for deterministic loss

typedef _Float16 half8 __attribute__((ext_vector_type(8)));
typedef float f32x4 __attribute__((ext_vector_type(4)));

static __device__ __forceinline__ void gload16(const uint4* g, uint4* l) {
    __builtin_amdgcn_global_load_lds(
        (const __attribute__((address_space(1))) unsigned int*)g,
        (__attribute__((address_space(3))) unsigned int*)l, 16, 0, 0);
}

// ---- prep: emb -> packed, pre-swizzled fp16 tiles of 64 codes + exact ||e||^2
// Bpk (uint4 granules of 8 fp16): [(t*64 + cl)*16 + (g ^ (cl&15))]
__global__ __launch_bounds__(128) void prep_kernel(const float* __restrict__ emb,
                                                   uint4* __restrict__ Bpk,
                                                   float* __restrict__ esq) {
    int k = blockIdx.x * 128 + threadIdx.x;
    if (k >= KCODES) return;
    int t = k >> 6, cl = k & 63;
    const float* e = emb + (size_t)k * CDIM;
    uint4* bp = Bpk + ((size_t)t * TCODES + cl) * 16;
    float s = 0.f;
#pragma unroll
    for (int g = 0; g < 16; g++) {
        unsigned hp[4];
#pragma unroll
        for (int p = 0; p < 4; p++) {
            float v0 = e[g * 8 + 2 * p + 0];
            float v1 = e[g * 8 + 2 * p + 1];
            union { _Float16 h[2]; unsigned u; } pk;
            pk.h[0] = (_Float16)v0;
            pk.h[1] = (_Float16)v1;
            hp[p] = pk.u;
            s = fmaf(v0, v0, s);
            s = fmaf(v1, v1, s);
        }
        bp[g ^ (cl & 15)] = make_uint4(hp[0], hp[1], hp[2], hp[3]);
    }
    esq[k] = s;
}

// ---- scoring + fused emit: fp16 single-pass, 3-deep counted-vmcnt pipeline --
__global__ __launch_bounds__(256, 3) void score_kernel(const float* __restrict__ in,
                                                       const uint4* __restrict__ Bpk,
                                                       const float* __restrict__ esq,
                                                       const float* __restrict__ emb,
                                                       float* __restrict__ out,
                                                       int* __restrict__ flag_list,
                                                       int* __restrict__ flag_cnt,
                                                       unsigned long long* __restrict__ loss_acc) {
    __shared__ uint4 BB[3][TCODES * 16];     // 3 x 16 KB ring
    __shared__ float b1L[128];
    __shared__ int   i1L[128];
    __shared__ float xsqL[128];
    __shared__ unsigned long long redL[16];

    const int tid = threadIdx.x;
    const int lane = tid & 63;
    const int w = tid >> 6;              // wave 0..3, owns rows w*32..w*32+31
    const int l15 = lane & 15;
    const int lg = lane >> 4;
    const int row0 = blockIdx.x * 128;
    const int b = row0 >> 15;
    const int sbase = (row0 & (SPATIAL - 1)) + w * 32;

#define STAGE(tt, bb)                                                     \
    do {                                                                  \
        const uint4* src_ = Bpk + (size_t)(tt) * 1024;                    \
        _Pragma("unroll")                                                 \
        for (int i_ = 0; i_ < 4; i_++)                                    \
            gload16(src_ + i_ * 256 + tid, &BB[bb][i_ * 256 + tid]);      \
    } while (0)

    STAGE(0, 0);   // tiles 0,1 DMA overlap the A-load below
    STAGE(1, 1);

    // ---- A fragments in registers: fp16, all K=128; exact ||x||^2 (fp32)
    half8 Af[8];                          // index [kk*2 + m]
    float xsq[2] = {0.f, 0.f};
    {
        const float* xb = in + (size_t)b * CDIM * SPATIAL;
#pragma unroll
        for (int kk = 0; kk < 4; kk++)
#pragma unroll
            for (int m = 0; m < 2; m++) {
                int srow = sbase + m * 16 + l15;
                union { unsigned u[4]; half8 h; } pk;
#pragma unroll
                for (int p = 0; p < 4; p++) {
                    int c0 = kk * 32 + lg * 8 + 2 * p;
                    float v0 = xb[(size_t)(c0 + 0) * SPATIAL + srow];
                    float v1 = xb[(size_t)(c0 + 1) * SPATIAL + srow];
                    union { _Float16 h[2]; unsigned u; } q;
                    q.h[0] = (_Float16)v0;
                    q.h[1] = (_Float16)v1;
                    pk.u[p] = q.u;
                    xsq[m] = fmaf(v0, v0, xsq[m]);
                    xsq[m] = fmaf(v1, v1, xsq[m]);
                }
                Af[kk * 2 + m] = pk.h;
            }
    }
    // reduce ||x||^2 over the 4 lg channel-groups
#pragma unroll
    for (int m = 0; m < 2; m++) {
        xsq[m] += __shfl_xor(xsq[m], 16);
        xsq[m] += __shfl_xor(xsq[m], 32);
    }
    if (lg == 0) {
        xsqL[w * 32 + l15] = xsq[0];
        xsqL[w * 32 + 16 + l15] = xsq[1];
    }

    float b1[8], b2[8];
    int i1[8];
#pragma unroll
    for (int i = 0; i < 8; i++) { b1[i] = FINF; b2[i] = FINF; i1[i] = 0; }

    for (int t = 0; t < NT; t++) {
        // tile t's DMA (issued >=2 iterations ago) must have landed; keep
        // tile t+1 (4 loads) in flight. Never vmcnt(0) mid-loop.
        if (t == NT - 1) asm volatile("s_waitcnt vmcnt(0)" ::: "memory");
        else             asm volatile("s_waitcnt vmcnt(4)" ::: "memory");
        __builtin_amdgcn_s_barrier();     // all waves' tile-t data visible;
                                          // all waves done reading buf (t+2)%3
        if (t + 2 < NT) STAGE(t + 2, (t + 2) % 3);

        const half8* Bs = reinterpret_cast<const half8*>(BB[t % 3]);
        f32x4 acc[2][4];
#pragma unroll
        for (int m = 0; m < 2; m++)
#pragma unroll
            for (int n = 0; n < 4; n++) acc[m][n] = (f32x4){0.f, 0.f, 0.f, 0.f};

#pragma unroll
        for (int kk = 0; kk < 4; kk++) {
            int phys = (kk * 4 + lg) ^ l15;
            half8 bv[4];
#pragma unroll
            for (int n = 0; n < 4; n++) bv[n] = Bs[(n * 16 + l15) * 16 + phys];
#pragma unroll
            for (int m = 0; m < 2; m++)
#pragma unroll
                for (int n = 0; n < 4; n++)
                    acc[m][n] = __builtin_amdgcn_mfma_f32_16x16x32_f16(Af[kk * 2 + m], bv[n], acc[m][n], 0, 0, 0);
        }

        // epilogue: s = ||e||^2 - 2*dot ; top1(val,idx) + top2(val)
#pragma unroll
        for (int n = 0; n < 4; n++) {
            int col = t * TCODES + n * 16 + l15;
            float ev = esq[col];
#pragma unroll
            for (int m = 0; m < 2; m++)
#pragma unroll
                for (int r = 0; r < 4; r++) {
                    float sv = fmaf(-2.f, acc[m][n][r], ev);
                    int slot = m * 4 + r;
                    bool c = sv < b1[slot];
                    b2[slot] = fminf(fmaxf(sv, b1[slot]), b2[slot]);   // med3
                    b1[slot] = fminf(sv, b1[slot]);
                    i1[slot] = c ? col : i1[slot];
                }
        }
    }
#undef STAGE

    // butterfly merge across the 16 col-lanes
#pragma unroll
    for (int j = 1; j < 16; j <<= 1) {
#pragma unroll
        for (int slot = 0; slot < 8; slot++) {
            float ob1 = __shfl_xor(b1[slot], j);
            float ob2 = __shfl_xor(b2[slot], j);
            int   oi  = __shfl_xor(i1[slot], j);
            bool take = (ob1 < b1[slot]) || (ob1 == b1[slot] && oi < i1[slot]);
            float nb2 = fminf(fmaxf(b1[slot], ob1), fminf(b2[slot], ob2));
            b1[slot] = take ? ob1 : b1[slot];
            i1[slot] = take ? oi : i1[slot];
            b2[slot] = nb2;
        }
    }

    __syncthreads();   // xsqL visible (also separates LDS reuse)

    if (l15 == 0) {
        unsigned long long lsum = 0;
#pragma unroll
        for (int m = 0; m < 2; m++)
#pragma unroll
            for (int r = 0; r < 4; r++) {
                int slot = m * 4 + r;
                int rl = w * 32 + m * 16 + lg * 4 + r;
                b1L[rl] = b1[slot];
                i1L[rl] = i1[slot];
                float cexp = b1[slot] + xsqL[rl];          // ||e||^2-2x.e+||x||^2
                unsigned long long ci = (unsigned long long)llrintf(cexp * LSCALE);
                if (b2[slot] - b1[slot] < MARGIN) {
                    int p = atomicAdd(flag_cnt, 1);
                    if (p < CAP) { flag_list[p] = row0 + rl; ci = 0; }  // refine adds exact
                }
                lsum += ci;
            }
        redL[w * 4 + lg] = lsum;
    }
    __syncthreads();
    if (tid == 0) {
        unsigned long long s = 0;
#pragma unroll
        for (int i = 0; i < 16; i++) s += redL[i];
        atomicAdd(loss_acc, s);
    }

    // ---- fused emit: idx, quantized (gather emb[k], channel-first write)
    {
        const int rl = w * 32 + (lane & 31);
        const int row = row0 + rl;
        const int sp = (row0 & (SPATIAL - 1)) + rl;
        const int k = i1L[rl];
        const int chalf = lane >> 5;

        if (chalf == 0) out[IDX_OFF + row] = (float)k;
        const float4* ep = reinterpret_cast<const float4*>(emb + (size_t)k * CDIM + chalf * 64);
        float* qout = out + (size_t)b * CDIM * SPATIAL + (size_t)chalf * 64 * SPATIAL + sp;
#pragma unroll
        for (int i = 0; i < 16; i++) {
            float4 v = ep[i];
            qout[(size_t)(4 * i + 0) * SPATIAL] = v.x;
            qout[(size_t)(4 * i + 1) * SPATIAL] = v.y;
            qout[(size_t)(4 * i + 2) * SPATIAL] = v.z;
            qout[(size_t)(4 * i + 3) * SPATIAL] = v.w;
        }
    }
}

// ---- refine: exact fp32 rescan of flagged rows; fixes idx, q row, loss -----
__global__ __launch_bounds__(128) void refine_kernel(const float* __restrict__ in,
                                                     const float* __restrict__ emb,
                                                     const float* __restrict__ esq,
                                                     const int* __restrict__ flag_list,
                                                     const int* __restrict__ flag_cnt,
                                                     float* __restrict__ out,
                                                     unsigned long long* __restrict__ loss_acc) {
    int n = *flag_cnt; if (n > CAP) n = CAP;
    if ((int)blockIdx.x >= n) return;
    __shared__ float xrow[CDIM];
    __shared__ float Ech[CDIM * 129];
    __shared__ float rv[128];
    __shared__ int   ri[128];

    const int t = threadIdx.x;
    const int row = flag_list[blockIdx.x];
    const int b = row >> 15, s = row & (SPATIAL - 1);
    xrow[t] = in[((size_t)b * CDIM + t) * SPATIAL + s];
    __syncthreads();

    float best = FINF; int bi = 0;
    for (int ch = 0; ch < 8; ch++) {
        const float4* src = reinterpret_cast<const float4*>(emb + (size_t)ch * 128 * CDIM);
#pragma unroll 4
        for (int i = t; i < 128 * 32; i += 128) {
            float4 v = src[i];
            int code = i >> 5, c4 = (i & 31) * 4;
            Ech[(c4 + 0) * 129 + code] = v.x;
            Ech[(c4 + 1) * 129 + code] = v.y;
            Ech[(c4 + 2) * 129 + code] = v.z;
            Ech[(c4 + 3) * 129 + code] = v.w;
        }
        __syncthreads();
        int k = ch * 128 + t;
        float dot = 0.f;
#pragma unroll 16
        for (int c = 0; c < CDIM; c++) dot = fmaf(xrow[c], Ech[c * 129 + t], dot);
        float d = fmaf(-2.f, dot, esq[k]);
        if (d < best) { best = d; bi = k; }
        __syncthreads();
    }
    rv[t] = best; ri[t] = bi;
    __syncthreads();
#pragma unroll
    for (int off = 64; off > 0; off >>= 1) {
        if (t < off) {
            bool take = (rv[t + off] < rv[t]) || (rv[t + off] == rv[t] && ri[t + off] < ri[t]);
            if (take) { rv[t] = rv[t + off]; ri[t] = ri[t + off]; }
        }
        __syncthreads();
    }
    const int kbest = ri[0];
    const float dbest = rv[0];
    __syncthreads();
    // exact ||x||^2 reduce
    rv[t] = xrow[t] * xrow[t];
    __syncthreads();
#pragma unroll
    for (int off = 64; off > 0; off >>= 1) {
        if (t < off) rv[t] += rv[t + off];
        __syncthreads();
    }
    if (t == 0) {
        out[IDX_OFF + row] = (float)kbest;
        atomicAdd(loss_acc, (unsigned long long)llrintf((dbest + rv[0]) * LSCALE));
    }
    // rewrite quantized row
    out[(size_t)b * CDIM * SPATIAL + (size_t)t * SPATIAL + s] = emb[(size_t)kbest * CDIM + t];
}

// ---- finalize: fixed-point -> float loss ------------------------------------
__global__ void finalize_kernel(const unsigned long long* __restrict__ loss_acc,
                                float* __restrict__ out) {
    double s = (double)*loss_acc / (double)LSCALE;
    out[LOSS_OFF] = (float)(0.25 * s / (double)Q_SIZE);
}

extern "C" void kernel_launch(void* const* d_in, const int* in_sizes, int n_in,
                              void* d_out, int out_size, void* d_ws, size_t ws_size,
                              hipStream_t stream) {
    const float* in = (const float*)d_in[0];
    const float* emb = (const float*)d_in[1];
    float* out = (float*)d_out;

    float* esq = (float*)d_ws;                                  // 4096 f32 (pad)
    uint4* Bpk = (uint4*)(esq + 4096);                          // 16384 uint4 (256 KB)
    unsigned long long* loss_acc = (unsigned long long*)(Bpk + KCODES * 16);
    int* flag_cnt = (int*)(loss_acc + 2);
    int* flag_list = flag_cnt + 4;                              // CAP i32

    hipMemsetAsync(loss_acc, 0, 8, stream);
    hipMemsetAsync(flag_cnt, 0, sizeof(int), stream);
    hipMemsetAsync(out + ESUM_OFF, 0, 256 * sizeof(float), stream);
    hipMemcpyAsync(out + EMB_OFF, emb, (size_t)KCODES * CDIM * sizeof(float),
                   hipMemcpyDeviceToDevice, stream);

    prep_kernel<<<KCODES / 128, 128, 0, stream>>>(emb, Bpk, esq);
    score_kernel<<<NROWS / 128, 256, 0, stream>>>(in, Bpk, esq, emb, out, flag_list, flag_cnt, loss_acc);
    refine_kernel<<<CAP, 128, 0, stream>>>(in, emb, esq, flag_list, flag_cnt, out, loss_acc);
    finalize_kernel<<<1, 1, 0, stream>>>(loss_acc, out);
}